// Round 8
// baseline (273.545 us; speedup 1.0000x reference)
//
#include <hip/hip_runtime.h>
#include <hip/hip_bf16.h>
#include <math.h>

// Problem: B=4, S=2048, D=1024, H=16, HD=64. M = B*S = 8192.

typedef short bf16x8 __attribute__((ext_vector_type(8)));
typedef float f32x4 __attribute__((ext_vector_type(4)));
typedef float f32x16 __attribute__((ext_vector_type(16)));
typedef unsigned short ushort8v __attribute__((ext_vector_type(8)));

#define MFMA16(a,b,c) __builtin_amdgcn_mfma_f32_16x16x32_bf16(a,b,c,0,0,0)
#define MFMA32(a,b,c) __builtin_amdgcn_mfma_f32_32x32x16_bf16(a,b,c,0,0,0)

__device__ __forceinline__ void gload16(const void* g, void* l) {
    __builtin_amdgcn_global_load_lds((const __attribute__((address_space(1))) void*)g,
                                     (__attribute__((address_space(3))) void*)l, 16, 0, 0);
}

// f32 -> bf16 RNE (no NaNs in this workload)
__device__ __forceinline__ unsigned short f2bf(float f) {
    unsigned int u = __float_as_uint(f);
    u += 0x7fffu + ((u >> 16) & 1u);
    return (unsigned short)(u >> 16);
}

__device__ __forceinline__ int cvtpk(float a, float b) {
    int r;
    asm("v_cvt_pk_bf16_f32 %0, %1, %2" : "=v"(r) : "v"(a), "v"(b));
    return r;
}

__device__ __forceinline__ float exp2a(float x) {   // v_exp_f32 is 2^x
    float r;
    asm("v_exp_f32 %0, %1" : "=v"(r) : "v"(x));
    return r;
}

__device__ __forceinline__ float max3f(float a, float b, float c) {
    float r;
    asm("v_max3_f32 %0, %1, %2, %3" : "=v"(r) : "v"(a), "v"(b), "v"(c));
    return r;
}

// Q pre-scale: 1/sqrt(64) * log2(e)  -> softmax in exp2 domain
#define QSCALE 0.18033688011112042f

// ---------------------------------------------------------------------------
// Convert X [8192*1024] f32 -> bf16
// ---------------------------------------------------------------------------
__global__ __launch_bounds__(256) void convert_x(const float* __restrict__ src,
                                                 unsigned short* __restrict__ dst) {
    int idx = (blockIdx.x * 256 + threadIdx.x) * 4;
    float4 v = *(const float4*)&src[idx];
    ushort4 o;
    o.x = f2bf(v.x); o.y = f2bf(v.y); o.z = f2bf(v.z); o.w = f2bf(v.w);
    *(ushort4*)&dst[idx] = o;
}

// ---------------------------------------------------------------------------
// Convert + transpose W [K=1024][N] f32 -> Wt [N][1024] bf16 (64x64 tiles)
// ---------------------------------------------------------------------------
__global__ __launch_bounds__(256) void convert_wt(const float* __restrict__ src,
                                                  unsigned short* __restrict__ dst, int N) {
    __shared__ float T[64][65];
    const int t = threadIdx.x;
    const int n0 = blockIdx.x * 64, k0 = blockIdx.y * 64;
    #pragma unroll
    for (int i = 0; i < 4; i++) {
        int row = (t >> 4) + 16 * i;        // k within tile
        int c4 = t & 15;
        float4 v = *(const float4*)&src[(size_t)(k0 + row) * N + n0 + c4 * 4];
        T[row][c4 * 4 + 0] = v.x; T[row][c4 * 4 + 1] = v.y;
        T[row][c4 * 4 + 2] = v.z; T[row][c4 * 4 + 3] = v.w;
    }
    __syncthreads();
    #pragma unroll
    for (int i = 0; i < 4; i++) {
        int n = (t >> 4) + 16 * i;
        int k4 = (t & 15) * 4;
        ushort4 o;
        o.x = f2bf(T[k4 + 0][n]); o.y = f2bf(T[k4 + 1][n]);
        o.z = f2bf(T[k4 + 2][n]); o.w = f2bf(T[k4 + 3][n]);
        *(ushort4*)&dst[(size_t)(n0 + n) * 1024 + k0 + k4] = o;
    }
}

// ---------------------------------------------------------------------------
// bf16 MFMA GEMM, 128x128 tile, BK=32, 4 waves (2x2), 16x16x32 MFMA.
// 2-phase prefetch (T3-minimum): double-buffered LDS; next tile's
// global_load_lds issued BEFORE ds_read+MFMA of current tile; ONE barrier
// per K-step (syncthreads drains vmcnt -> next buffer ready).
// ---------------------------------------------------------------------------
template<int MODE>
__global__ __launch_bounds__(256) void gemm_mfma(
        const unsigned short* __restrict__ A, const unsigned short* __restrict__ Bt,
        const float* __restrict__ bias,
        unsigned short* __restrict__ Qp, unsigned short* __restrict__ Kp,
        unsigned short* __restrict__ Vp, float* __restrict__ OUT) {
    __shared__ __align__(16) unsigned short Al[2][128 * 32];
    __shared__ __align__(16) unsigned short Bl[2][128 * 32];
    const int tid = threadIdx.x;
    const int l = tid & 63, w = tid >> 6;
    const int wm = w >> 1, wn = w & 1;
    const int m0 = blockIdx.y * 128, n0 = blockIdx.x * 128;
    const int l15 = l & 15, l4 = l >> 4;

    f32x4 acc[4][4] = {};

    int bb = 0, s0 = 0;
    if (MODE == 1) { bb = m0 >> 11; s0 = m0 & 2047; }

    auto stage = [&](int buf, int k0) {
        #pragma unroll
        for (int p = 0; p < 2; p++) {
            int idx = tid + 256 * p;
            int row = idx >> 2, sl = idx & 3;
            int gc = sl ^ (row & 3);
            const unsigned short* ga;
            if (MODE == 0) {
                ga = A + (size_t)(m0 + row) * 1024 + k0 + gc * 8;
            } else {
                int h = k0 >> 6;
                ga = A + ((size_t)(bb * 16 + h) * 2048 + s0 + row) * 64 + (k0 & 63) + gc * 8;
            }
            gload16(ga, (char*)Al[buf] + w * 1024 + p * 4096);
            const unsigned short* gb = Bt + (size_t)(n0 + row) * 1024 + k0 + gc * 8;
            gload16(gb, (char*)Bl[buf] + w * 1024 + p * 4096);
        }
    };

    stage(0, 0);
    __syncthreads();                      // tile 0 resident

    for (int t = 0; t < 32; t++) {
        const int buf = t & 1;
        if (t < 31) stage(buf ^ 1, (t + 1) * 32);   // prefetch next (in flight over MFMA)

        bf16x8 af[4], bfr[4];
        #pragma unroll
        for (int mi = 0; mi < 4; mi++) {
            int row = 64 * wm + 16 * mi + l15;
            af[mi] = *(const bf16x8*)((const char*)Al[buf] + row * 64 + ((l4 ^ (l15 & 3)) * 16));
        }
        #pragma unroll
        for (int ni = 0; ni < 4; ni++) {
            int row = 64 * wn + 16 * ni + l15;
            bfr[ni] = *(const bf16x8*)((const char*)Bl[buf] + row * 64 + ((l4 ^ (l15 & 3)) * 16));
        }
        __builtin_amdgcn_s_setprio(1);
        #pragma unroll
        for (int mi = 0; mi < 4; mi++)
            #pragma unroll
            for (int ni = 0; ni < 4; ni++)
                acc[mi][ni] = MFMA16(af[mi], bfr[ni], acc[mi][ni]);
        __builtin_amdgcn_s_setprio(0);

        __syncthreads();                  // drains vmcnt: prefetched tile ready
    }

    if (MODE == 0) {
        const int qsel = n0 >> 10;
        unsigned short* dst = (qsel == 0) ? Qp : (qsel == 1) ? Kp : Vp;
        const float scale = (qsel == 0) ? QSCALE : 1.0f;
        const int h = ((n0 + 64 * wn) >> 6) & 15;
        #pragma unroll
        for (int ni = 0; ni < 4; ni++) {
            const int hd = 16 * ni + l15;
            const int ng = n0 + 64 * wn + hd;
            const float bv = bias[ng];
            #pragma unroll
            for (int mi = 0; mi < 4; mi++) {
                #pragma unroll
                for (int bi = 0; bi < 4; bi++) {
                    int m = m0 + 64 * wm + 16 * mi + 4 * l4 + bi;
                    int b_ = m >> 11, s = m & 2047;
                    float v = (acc[mi][ni][bi] + bv) * scale;
                    dst[((size_t)(b_ * 16 + h) * 2048 + s) * 64 + hd] = f2bf(v);
                }
            }
        }
    } else {
        #pragma unroll
        for (int ni = 0; ni < 4; ni++) {
            const int ng = n0 + 64 * wn + 16 * ni + l15;
            const float bv = bias[ng];
            #pragma unroll
            for (int mi = 0; mi < 4; mi++) {
                #pragma unroll
                for (int bi = 0; bi < 4; bi++) {
                    int m = m0 + 64 * wm + 16 * mi + 4 * l4 + bi;
                    OUT[(size_t)m * 1024 + ng] = acc[mi][ni][bi] + bv;
                }
            }
        }
    }
}

// ---------------------------------------------------------------------------
// MFMA flash attention, 8 waves/block (512 thr). Causal pair IN-block:
// waves 0-3 own q-tile pid, waves 4-7 own q-tile 15-pid, sharing one staged
// K/V tile stream. (UNCHANGED from round 7 - control for this experiment.)
// ---------------------------------------------------------------------------
__global__ __launch_bounds__(512, 4) void attn_mfma(
        const unsigned short* __restrict__ Q, const unsigned short* __restrict__ K,
        const unsigned short* __restrict__ V, unsigned short* __restrict__ AO) {
    __shared__ __align__(16) char smem[18432];
    unsigned short* Vl = (unsigned short*)(smem + 8192);   // V^T [64][72]
    const int tid = threadIdx.x;
    const int l = tid & 63, w = tid >> 6;       // w 0..7
    const int hi = l >> 5, q31 = l & 31;
    const int bh = blockIdx.x & 63;
    const int g = blockIdx.x >> 6;              // 0..7
    const int pid = (g < 4) ? g : 11 - g;       // pairs (0,7),(1,6),(2,5),(3,4)
    const int qi = (w >= 4) ? (15 - pid) : pid;
    const int q0 = qi * 128 + 32 * (w & 3);
    const int qg = q0 + q31;
    const unsigned short* qb = Q + (size_t)bh * 2048 * 64;
    const unsigned short* kb = K + (size_t)bh * 2048 * 64;
    const unsigned short* vb = V + (size_t)bh * 2048 * 64;
    unsigned short* ob = AO + (size_t)bh * 2048 * 64;

    bf16x8 qf[4];
    #pragma unroll
    for (int kk = 0; kk < 4; kk++)
        qf[kk] = *(const bf16x8*)&qb[(size_t)qg * 64 + 16 * kk + 8 * hi];

    f32x16 oa[2] = {};
    float mx = -INFINITY, ls = 0.0f;

    const int TMAX = 32 - 2 * pid;              // = long half's tile count
    #pragma unroll 1
    for (int t = 0; t < TMAX; t++) {
        const int kv0 = 64 * t;
        __syncthreads();
        if (w >= 4) {
            // stage K via global_load_lds, source-swizzled (slot s <- chunk s^(row&7))
            int t2 = tid - 256;
            #pragma unroll
            for (int p = 0; p < 2; p++) {
                int idx = t2 + 256 * p;
                int row = idx >> 3, sl = idx & 7;
                gload16(kb + (size_t)(kv0 + row) * 64 + ((sl ^ (row & 7)) * 8),
                        smem + (w - 4) * 1024 + p * 4096);
            }
        } else {
            // stage V transposed: key-pair b32 pack, j-rotated (2-way max)
            int kg = tid >> 3, hg = tid & 7;    // kg 0..31 -> keys 2kg,2kg+1
            ushort8v v0 = *(const ushort8v*)&vb[(size_t)(kv0 + 2 * kg) * 64 + hg * 8];
            ushort8v v1 = *(const ushort8v*)&vb[(size_t)(kv0 + 2 * kg + 1) * 64 + hg * 8];
            #pragma unroll
            for (int i = 0; i < 8; i++) {
                int j = (i + tid) & 7;
                unsigned int pk = (unsigned int)(unsigned short)v0[j] |
                                  ((unsigned int)(unsigned short)v1[j] << 16);
                *(unsigned int*)((char*)Vl + (hg * 8 + j) * 144 + kg * 4) = pk;
            }
        }
        __syncthreads();

        #pragma unroll
        for (int st = 0; st < 2; st++) {
            const int k0g = kv0 + 32 * st;
            if (k0g <= q0 + 31) {                       // wave-uniform causal skip
                f32x16 sa = {};
                __builtin_amdgcn_s_setprio(1);
                #pragma unroll
                for (int kk = 0; kk < 4; kk++) {
                    bf16x8 kf = *(const bf16x8*)((const char*)smem +
                        (32 * st + q31) * 128 + (((2 * kk + hi) ^ (l & 7)) * 16));
                    sa = MFMA32(kf, qf[kk], sa);
                }
                __builtin_amdgcn_s_setprio(0);
                float sv[16];
                #pragma unroll
                for (int r = 0; r < 16; r++) sv[r] = sa[r];
                if (k0g + 31 > q0) {                    // diagonal tile: mask
                    #pragma unroll
                    for (int r = 0; r < 16; r++) {
                        int key = k0g + (r & 3) + 8 * (r >> 2) + 4 * hi;
                        if (key > qg) sv[r] = -INFINITY;
                    }
                }
                float m16 = max3f(sv[0], sv[1], sv[2]);
                m16 = max3f(m16, sv[3], sv[4]);
                m16 = max3f(m16, sv[5], sv[6]);
                m16 = max3f(m16, sv[7], sv[8]);
                m16 = max3f(m16, sv[9], sv[10]);
                m16 = max3f(m16, sv[11], sv[12]);
                m16 = max3f(m16, sv[13], sv[14]);
                m16 = fmaxf(m16, sv[15]);
                float mo = fmaxf(m16, __shfl_xor(m16, 32));
                // defer-max: skip rescale while growth <= 8 (p <= 2^8)
                if (!__all(mo <= mx + 8.0f)) {
                    float mn = fmaxf(mx, mo);
                    float sc = exp2a(mx - mn);
                    mx = mn;
                    ls *= sc;
                    oa[0] *= sc;
                    oa[1] *= sc;
                }
                float ps = 0.0f;
                #pragma unroll
                for (int r = 0; r < 16; r++) { sv[r] = exp2a(sv[r] - mx); ps += sv[r]; }
                ls += ps + __shfl_xor(ps, 32);
                // P^T bf16 B-frags: words 0,1 from lo-half lanes, 2,3 from hi-half
                int pw[2][4];
                #pragma unroll
                for (int mm = 0; mm < 2; mm++) {
                    int x0 = cvtpk(sv[8 * mm + 0], sv[8 * mm + 1]);
                    int x1 = cvtpk(sv[8 * mm + 2], sv[8 * mm + 3]);
                    int y0 = cvtpk(sv[8 * mm + 4], sv[8 * mm + 5]);
                    int y1 = cvtpk(sv[8 * mm + 6], sv[8 * mm + 7]);
                    int sx0 = __shfl_xor(x0, 32), sx1 = __shfl_xor(x1, 32);
                    int sy0 = __shfl_xor(y0, 32), sy1 = __shfl_xor(y1, 32);
                    pw[mm][0] = hi ? sy0 : x0;
                    pw[mm][1] = hi ? sy1 : x1;
                    pw[mm][2] = hi ? y0 : sx0;
                    pw[mm][3] = hi ? y1 : sx1;
                }
                __builtin_amdgcn_s_setprio(1);
                #pragma unroll
                for (int ch = 0; ch < 2; ch++) {
                    #pragma unroll
                    for (int mm = 0; mm < 2; mm++) {
                        int hd = 32 * ch + q31;
                        bf16x8 vf = *(const bf16x8*)((const char*)Vl +
                            hd * 144 + (32 * st + 16 * mm + 8 * hi) * 2);
                        union { int i[4]; bf16x8 v; } pu;
                        pu.i[0] = pw[mm][0]; pu.i[1] = pw[mm][1];
                        pu.i[2] = pw[mm][2]; pu.i[3] = pw[mm][3];
                        oa[ch] = MFMA32(vf, pu.v, oa[ch]);
                    }
                }
                __builtin_amdgcn_s_setprio(0);
            }
        }
    }

    float inv = 1.0f / ls;
    oa[0] *= inv;
    oa[1] *= inv;
    __syncthreads();   // all waves done with K/V LDS
    // O transpose via per-wave scratch [32 q][72 u16], 2 passes (4 waves each)
    #pragma unroll 1
    for (int pass = 0; pass < 2; pass++) {
        if ((w >> 2) == pass) {
            unsigned short* Ol = (unsigned short*)(smem + (w & 3) * 4608);
            #pragma unroll
            for (int ch = 0; ch < 2; ch++)
                #pragma unroll
                for (int r = 0; r < 16; r++) {
                    int hd = (r & 3) + 8 * (r >> 2) + 4 * hi + 32 * ch;
                    Ol[q31 * 72 + hd] = f2bf(oa[ch][r]);
                }
            asm volatile("s_waitcnt lgkmcnt(0)" ::: "memory");
            int row = l >> 1;
            #pragma unroll
            for (int c = 0; c < 4; c++) {
                int col = (4 * (l & 1) + c) * 8;
                bf16x8 ov = *(const bf16x8*)((const char*)Ol + row * 144 + col * 2);
                *(bf16x8*)&ob[(size_t)(q0 + row) * 64 + col] = ov;
            }
        }
        __syncthreads();
    }
}

// ---------------------------------------------------------------------------
extern "C" void kernel_launch(void* const* d_in, const int* in_sizes, int n_in,
                              void* d_out, int out_size, void* d_ws, size_t ws_size,
                              hipStream_t stream) {
    const float* x      = (const float*)d_in[0];
    // d_in[1] = padding_mask (all true) - unused
    const float* W_attn = (const float*)d_in[2];
    const float* b_attn = (const float*)d_in[3];
    const float* W_proj = (const float*)d_in[4];
    const float* b_proj = (const float*)d_in[5];
    float* out = (float*)d_out;

    char* ws = (char*)d_ws;
    unsigned short* Xb  = (unsigned short*)(ws);               // 16.78 MB
    unsigned short* Wat = (unsigned short*)(ws + 16777216);    //  6.29 MB [3072][1024]
    unsigned short* Wpt = (unsigned short*)(ws + 23068672);    //  2.10 MB [1024][1024]
    unsigned short* Qb  = (unsigned short*)(ws + 25165824);    // 16.78 MB [B,H,S,HD]
    unsigned short* Kb  = (unsigned short*)(ws + 41943040);
    unsigned short* Vb  = (unsigned short*)(ws + 58720256);
    unsigned short* AOb = (unsigned short*)(ws + 75497472);    // 16.78 MB

    convert_x<<<8192, 256, 0, stream>>>(x, Xb);
    convert_wt<<<dim3(48, 16), 256, 0, stream>>>(W_attn, Wat, 3072);
    convert_wt<<<dim3(16, 16), 256, 0, stream>>>(W_proj, Wpt, 1024);

    gemm_mfma<0><<<dim3(24, 64), 256, 0, stream>>>(Xb, Wat, b_attn, Qb, Kb, Vb, nullptr);
    attn_mfma<<<512, 512, 0, stream>>>(Qb, Kb, Vb, AOb);
    gemm_mfma<1><<<dim3(8, 64), 256, 0, stream>>>(AOb, Wpt, b_proj, nullptr, nullptr, nullptr, out);
}

// Round 9
// 263.009 us; speedup vs baseline: 1.0401x; 1.0401x over previous
//
#include <hip/hip_runtime.h>
#include <hip/hip_bf16.h>
#include <math.h>

// Problem: B=4, S=2048, D=1024, H=16, HD=64. M = B*S = 8192.

typedef short bf16x8 __attribute__((ext_vector_type(8)));
typedef float f32x4 __attribute__((ext_vector_type(4)));
typedef float f32x16 __attribute__((ext_vector_type(16)));
typedef unsigned short ushort8v __attribute__((ext_vector_type(8)));

#define MFMA16(a,b,c) __builtin_amdgcn_mfma_f32_16x16x32_bf16(a,b,c,0,0,0)
#define MFMA32(a,b,c) __builtin_amdgcn_mfma_f32_32x32x16_bf16(a,b,c,0,0,0)

__device__ __forceinline__ void gload16(const void* g, void* l) {
    __builtin_amdgcn_global_load_lds((const __attribute__((address_space(1))) void*)g,
                                     (__attribute__((address_space(3))) void*)l, 16, 0, 0);
}

// f32 -> bf16 RNE (no NaNs in this workload)
__device__ __forceinline__ unsigned short f2bf(float f) {
    unsigned int u = __float_as_uint(f);
    u += 0x7fffu + ((u >> 16) & 1u);
    return (unsigned short)(u >> 16);
}

__device__ __forceinline__ int cvtpk(float a, float b) {
    int r;
    asm("v_cvt_pk_bf16_f32 %0, %1, %2" : "=v"(r) : "v"(a), "v"(b));
    return r;
}

__device__ __forceinline__ float exp2a(float x) {   // v_exp_f32 is 2^x
    float r;
    asm("v_exp_f32 %0, %1" : "=v"(r) : "v"(x));
    return r;
}

__device__ __forceinline__ float max3f(float a, float b, float c) {
    float r;
    asm("v_max3_f32 %0, %1, %2, %3" : "=v"(r) : "v"(a), "v"(b), "v"(c));
    return r;
}

// Q pre-scale: 1/sqrt(64) * log2(e)  -> softmax in exp2 domain
#define QSCALE 0.18033688011112042f

// ---------------------------------------------------------------------------
// Convert X [8192*1024] f32 -> bf16
// ---------------------------------------------------------------------------
__global__ __launch_bounds__(256) void convert_x(const float* __restrict__ src,
                                                 unsigned short* __restrict__ dst) {
    int idx = (blockIdx.x * 256 + threadIdx.x) * 4;
    float4 v = *(const float4*)&src[idx];
    ushort4 o;
    o.x = f2bf(v.x); o.y = f2bf(v.y); o.z = f2bf(v.z); o.w = f2bf(v.w);
    *(ushort4*)&dst[idx] = o;
}

// ---------------------------------------------------------------------------
// Convert + transpose W [K=1024][N] f32 -> Wt [N][1024] bf16 (64x64 tiles)
// ---------------------------------------------------------------------------
__global__ __launch_bounds__(256) void convert_wt(const float* __restrict__ src,
                                                  unsigned short* __restrict__ dst, int N) {
    __shared__ float T[64][65];
    const int t = threadIdx.x;
    const int n0 = blockIdx.x * 64, k0 = blockIdx.y * 64;
    #pragma unroll
    for (int i = 0; i < 4; i++) {
        int row = (t >> 4) + 16 * i;        // k within tile
        int c4 = t & 15;
        float4 v = *(const float4*)&src[(size_t)(k0 + row) * N + n0 + c4 * 4];
        T[row][c4 * 4 + 0] = v.x; T[row][c4 * 4 + 1] = v.y;
        T[row][c4 * 4 + 2] = v.z; T[row][c4 * 4 + 3] = v.w;
    }
    __syncthreads();
    #pragma unroll
    for (int i = 0; i < 4; i++) {
        int n = (t >> 4) + 16 * i;
        int k4 = (t & 15) * 4;
        ushort4 o;
        o.x = f2bf(T[k4 + 0][n]); o.y = f2bf(T[k4 + 1][n]);
        o.z = f2bf(T[k4 + 2][n]); o.w = f2bf(T[k4 + 3][n]);
        *(ushort4*)&dst[(size_t)(n0 + n) * 1024 + k0 + k4] = o;
    }
}

// ---------------------------------------------------------------------------
// bf16 MFMA GEMM, 128x128 tile, BK=32, 4 waves (2x2), 16x16x32 MFMA.
// T4 counted-vmcnt pipeline: double-buffered LDS, raw s_barrier, vmcnt(4)
// mid-loop (tile t+1 stays in flight across the barrier). Tile t's loads get
// a full iteration of latency cover. Tail: t=31 -> vmcnt(0).
// ---------------------------------------------------------------------------
template<int MODE>
__global__ __launch_bounds__(256) void gemm_mfma(
        const unsigned short* __restrict__ A, const unsigned short* __restrict__ Bt,
        const float* __restrict__ bias,
        unsigned short* __restrict__ Qp, unsigned short* __restrict__ Kp,
        unsigned short* __restrict__ Vp, float* __restrict__ OUT) {
    __shared__ __align__(16) unsigned short Al[2][128 * 32];
    __shared__ __align__(16) unsigned short Bl[2][128 * 32];
    const int tid = threadIdx.x;
    const int l = tid & 63, w = tid >> 6;
    const int wm = w >> 1, wn = w & 1;
    const int m0 = blockIdx.y * 128, n0 = blockIdx.x * 128;
    const int l15 = l & 15, l4 = l >> 4;

    f32x4 acc[4][4] = {};

    int bb = 0, s0 = 0;
    if (MODE == 1) { bb = m0 >> 11; s0 = m0 & 2047; }

    auto stage = [&](int buf, int k0) {
        #pragma unroll
        for (int p = 0; p < 2; p++) {
            int idx = tid + 256 * p;
            int row = idx >> 2, sl = idx & 3;
            int gc = sl ^ (row & 3);
            const unsigned short* ga;
            if (MODE == 0) {
                ga = A + (size_t)(m0 + row) * 1024 + k0 + gc * 8;
            } else {
                int h = k0 >> 6;
                ga = A + ((size_t)(bb * 16 + h) * 2048 + s0 + row) * 64 + (k0 & 63) + gc * 8;
            }
            gload16(ga, (char*)Al[buf] + w * 1024 + p * 4096);
            const unsigned short* gb = Bt + (size_t)(n0 + row) * 1024 + k0 + gc * 8;
            gload16(gb, (char*)Bl[buf] + w * 1024 + p * 4096);
        }
    };

    stage(0, 0);
    stage(1, 32);

    #pragma unroll 1
    for (int t = 0; t < 32; t++) {
        const int buf = t & 1;
        if (t < 31) asm volatile("s_waitcnt vmcnt(4)" ::: "memory");
        else        asm volatile("s_waitcnt vmcnt(0)" ::: "memory");
        __builtin_amdgcn_s_barrier();
        asm volatile("" ::: "memory");

        bf16x8 af[4], bfr[4];
        #pragma unroll
        for (int mi = 0; mi < 4; mi++) {
            int row = 64 * wm + 16 * mi + l15;
            af[mi] = *(const bf16x8*)((const char*)Al[buf] + row * 64 + ((l4 ^ (l15 & 3)) * 16));
        }
        #pragma unroll
        for (int ni = 0; ni < 4; ni++) {
            int row = 64 * wn + 16 * ni + l15;
            bfr[ni] = *(const bf16x8*)((const char*)Bl[buf] + row * 64 + ((l4 ^ (l15 & 3)) * 16));
        }
        __builtin_amdgcn_s_setprio(1);
        #pragma unroll
        for (int mi = 0; mi < 4; mi++)
            #pragma unroll
            for (int ni = 0; ni < 4; ni++)
                acc[mi][ni] = MFMA16(af[mi], bfr[ni], acc[mi][ni]);
        __builtin_amdgcn_s_setprio(0);

        asm volatile("" ::: "memory");
        __builtin_amdgcn_s_barrier();        // all waves done reading buf
        if (t < 30) stage(buf, (t + 2) * 32);
    }

    if (MODE == 0) {
        const int qsel = n0 >> 10;
        unsigned short* dst = (qsel == 0) ? Qp : (qsel == 1) ? Kp : Vp;
        const float scale = (qsel == 0) ? QSCALE : 1.0f;
        const int h = ((n0 + 64 * wn) >> 6) & 15;
        #pragma unroll
        for (int ni = 0; ni < 4; ni++) {
            const int hd = 16 * ni + l15;
            const int ng = n0 + 64 * wn + hd;
            const float bv = bias[ng];
            #pragma unroll
            for (int mi = 0; mi < 4; mi++) {
                #pragma unroll
                for (int bi = 0; bi < 4; bi++) {
                    int m = m0 + 64 * wm + 16 * mi + 4 * l4 + bi;
                    int b_ = m >> 11, s = m & 2047;
                    float v = (acc[mi][ni][bi] + bv) * scale;
                    dst[((size_t)(b_ * 16 + h) * 2048 + s) * 64 + hd] = f2bf(v);
                }
            }
        }
    } else {
        #pragma unroll
        for (int ni = 0; ni < 4; ni++) {
            const int ng = n0 + 64 * wn + 16 * ni + l15;
            const float bv = bias[ng];
            #pragma unroll
            for (int mi = 0; mi < 4; mi++) {
                #pragma unroll
                for (int bi = 0; bi < 4; bi++) {
                    int m = m0 + 64 * wm + 16 * mi + 4 * l4 + bi;
                    OUT[(size_t)m * 1024 + ng] = acc[mi][ni][bi] + bv;
                }
            }
        }
    }
}

// ---------------------------------------------------------------------------
// MFMA flash attention, 8 waves/block. Causal pair IN-block (waves 0-3 tile
// pid, waves 4-7 tile 15-pid). Double-buffered K (2x8KB, gload_lds by w>=4)
// and V^T (2x9KB 144B-stride, reg-staged by w<4). T14 schedule per tile:
//   top:  w>=4 issue K(t+1)->Kbuf^1 then vmcnt(2) [K(t) landed, K(t+1) flies]
//         w<4  issue V(t+1)->regs (no wait)
//   barrier; compute(t); barrier;
//   w<4: vmcnt(0) [V(t+1) regs landed under compute]; ds_write Vbuf^1;
//        lgkmcnt(0) [visible at next barrier]
// Raw s_barrier throughout (no vmcnt-0 drain mid-loop).
// ---------------------------------------------------------------------------
__global__ __launch_bounds__(512, 4) void attn_mfma(
        const unsigned short* __restrict__ Q, const unsigned short* __restrict__ K,
        const unsigned short* __restrict__ V, unsigned short* __restrict__ AO) {
    __shared__ __align__(16) char smem[34816];
    // layout: K0 @0 (8KB), K1 @8192, V0 @16384 (9216B), V1 @25600
    const int tid = threadIdx.x;
    const int l = tid & 63, w = tid >> 6;       // w 0..7
    const int hi = l >> 5, q31 = l & 31;
    const int bh = blockIdx.x & 63;
    const int g = blockIdx.x >> 6;              // 0..7
    const int pid = (g < 4) ? g : 11 - g;       // pairs complementary per CU
    const int qi = (w >= 4) ? (15 - pid) : pid;
    const int q0 = qi * 128 + 32 * (w & 3);
    const int qg = q0 + q31;
    const unsigned short* qb = Q + (size_t)bh * 2048 * 64;
    const unsigned short* kb = K + (size_t)bh * 2048 * 64;
    const unsigned short* vb = V + (size_t)bh * 2048 * 64;
    unsigned short* ob = AO + (size_t)bh * 2048 * 64;

    bf16x8 qf[4];
    #pragma unroll
    for (int kk = 0; kk < 4; kk++)
        qf[kk] = *(const bf16x8*)&qb[(size_t)qg * 64 + 16 * kk + 8 * hi];

    f32x16 oa[2] = {};
    float mx = -INFINITY, ls = 0.0f;

    const int TMAX = 32 - 2 * pid;              // >= 18

    const int kg = tid >> 3, hg = tid & 7;      // V staging coords (w<4)
    const int t2 = tid & 255;                   // K staging coords (w>=4)

    auto stageK = [&](int t, char* dst) {       // w>=4 only: 2 gload_lds
        #pragma unroll
        for (int p = 0; p < 2; p++) {
            int idx = t2 + 256 * p;
            int row = idx >> 3, sl = idx & 7;
            gload16(kb + (size_t)(64 * t + row) * 64 + ((sl ^ (row & 7)) * 8),
                    dst + (w - 4) * 1024 + p * 4096);
        }
    };
    ushort8v va, vbr;
    auto loadV = [&](int t) {                   // w<4 only: global->regs
        va  = *(const ushort8v*)&vb[(size_t)(64 * t + 2 * kg) * 64 + hg * 8];
        vbr = *(const ushort8v*)&vb[(size_t)(64 * t + 2 * kg + 1) * 64 + hg * 8];
    };
    auto writeV = [&](char* Vdst) {             // w<4 only: packed b32, j-rotated
        #pragma unroll
        for (int i = 0; i < 8; i++) {
            int j = (i + tid) & 7;
            unsigned int pk = (unsigned int)(unsigned short)va[j] |
                              ((unsigned int)(unsigned short)vbr[j] << 16);
            *(unsigned int*)(Vdst + (hg * 8 + j) * 144 + kg * 4) = pk;
        }
    };

    // prologue: tile 0
    if (w >= 4) {
        stageK(0, smem);
    } else {
        loadV(0);
        asm volatile("s_waitcnt vmcnt(0)" ::: "memory");
        writeV(smem + 16384);
        asm volatile("s_waitcnt lgkmcnt(0)" ::: "memory");
    }

    #pragma unroll 1
    for (int t = 0; t < TMAX; t++) {
        const int cur = t & 1;
        char* Kcur = smem + cur * 8192;
        char* Vcur = smem + 16384 + cur * 9216;
        // --- staging top: issue t+1, wait only what's needed ---
        if (w >= 4) {
            if (t + 1 < TMAX) {
                stageK(t + 1, smem + (cur ^ 1) * 8192);
                asm volatile("s_waitcnt vmcnt(2)" ::: "memory");   // K(t) landed
            } else {
                asm volatile("s_waitcnt vmcnt(0)" ::: "memory");
            }
        } else {
            if (t + 1 < TMAX) loadV(t + 1);     // flies under compute
        }
        __builtin_amdgcn_s_barrier();
        asm volatile("" ::: "memory");

        #pragma unroll
        for (int st = 0; st < 2; st++) {
            const int k0g = 64 * t + 32 * st;
            if (k0g <= q0 + 31) {                       // wave-uniform causal skip
                f32x16 sa = {};
                __builtin_amdgcn_s_setprio(1);
                #pragma unroll
                for (int kk = 0; kk < 4; kk++) {
                    bf16x8 kf = *(const bf16x8*)(Kcur +
                        (32 * st + q31) * 128 + (((2 * kk + hi) ^ (l & 7)) * 16));
                    sa = MFMA32(kf, qf[kk], sa);
                }
                __builtin_amdgcn_s_setprio(0);
                float sv[16];
                #pragma unroll
                for (int r = 0; r < 16; r++) sv[r] = sa[r];
                if (k0g + 31 > q0) {                    // diagonal tile: mask
                    #pragma unroll
                    for (int r = 0; r < 16; r++) {
                        int key = k0g + (r & 3) + 8 * (r >> 2) + 4 * hi;
                        if (key > qg) sv[r] = -INFINITY;
                    }
                }
                float m16 = max3f(sv[0], sv[1], sv[2]);
                m16 = max3f(m16, sv[3], sv[4]);
                m16 = max3f(m16, sv[5], sv[6]);
                m16 = max3f(m16, sv[7], sv[8]);
                m16 = max3f(m16, sv[9], sv[10]);
                m16 = max3f(m16, sv[11], sv[12]);
                m16 = max3f(m16, sv[13], sv[14]);
                m16 = fmaxf(m16, sv[15]);
                float mo = fmaxf(m16, __shfl_xor(m16, 32));
                // defer-max: skip rescale while growth <= 8 (p <= 2^8)
                if (!__all(mo <= mx + 8.0f)) {
                    float mn = fmaxf(mx, mo);
                    float sc = exp2a(mx - mn);
                    mx = mn;
                    ls *= sc;
                    oa[0] *= sc;
                    oa[1] *= sc;
                }
                float ps = 0.0f;
                #pragma unroll
                for (int r = 0; r < 16; r++) { sv[r] = exp2a(sv[r] - mx); ps += sv[r]; }
                ls += ps + __shfl_xor(ps, 32);
                // P^T bf16 B-frags: words 0,1 from lo-half lanes, 2,3 from hi-half
                int pw[2][4];
                #pragma unroll
                for (int mm = 0; mm < 2; mm++) {
                    int x0 = cvtpk(sv[8 * mm + 0], sv[8 * mm + 1]);
                    int x1 = cvtpk(sv[8 * mm + 2], sv[8 * mm + 3]);
                    int y0 = cvtpk(sv[8 * mm + 4], sv[8 * mm + 5]);
                    int y1 = cvtpk(sv[8 * mm + 6], sv[8 * mm + 7]);
                    int sx0 = __shfl_xor(x0, 32), sx1 = __shfl_xor(x1, 32);
                    int sy0 = __shfl_xor(y0, 32), sy1 = __shfl_xor(y1, 32);
                    pw[mm][0] = hi ? sy0 : x0;
                    pw[mm][1] = hi ? sy1 : x1;
                    pw[mm][2] = hi ? y0 : sx0;
                    pw[mm][3] = hi ? y1 : sx1;
                }
                __builtin_amdgcn_s_setprio(1);
                #pragma unroll
                for (int ch = 0; ch < 2; ch++) {
                    #pragma unroll
                    for (int mm = 0; mm < 2; mm++) {
                        int hd = 32 * ch + q31;
                        bf16x8 vf = *(const bf16x8*)(Vcur +
                            hd * 144 + (32 * st + 16 * mm + 8 * hi) * 2);
                        union { int i[4]; bf16x8 v; } pu;
                        pu.i[0] = pw[mm][0]; pu.i[1] = pw[mm][1];
                        pu.i[2] = pw[mm][2]; pu.i[3] = pw[mm][3];
                        oa[ch] = MFMA32(vf, pu.v, oa[ch]);
                    }
                }
                __builtin_amdgcn_s_setprio(0);
            }
        }

        asm volatile("" ::: "memory");
        __builtin_amdgcn_s_barrier();           // all done reading cur buffers
        if (w < 4 && t + 1 < TMAX) {
            asm volatile("s_waitcnt vmcnt(0)" ::: "memory");   // V(t+1) regs landed
            writeV(smem + 16384 + (cur ^ 1) * 9216);
            asm volatile("s_waitcnt lgkmcnt(0)" ::: "memory"); // visible by next barrier
        }
    }

    float inv = 1.0f / ls;
    oa[0] *= inv;
    oa[1] *= inv;
    __syncthreads();   // all waves done with K/V LDS; full drain before reuse
    // O transpose via per-wave scratch [32 q][72 u16], 2 passes (4 waves each)
    #pragma unroll 1
    for (int pass = 0; pass < 2; pass++) {
        if ((w >> 2) == pass) {
            unsigned short* Ol = (unsigned short*)(smem + (w & 3) * 4608);
            #pragma unroll
            for (int ch = 0; ch < 2; ch++)
                #pragma unroll
                for (int r = 0; r < 16; r++) {
                    int hd = (r & 3) + 8 * (r >> 2) + 4 * hi + 32 * ch;
                    Ol[q31 * 72 + hd] = f2bf(oa[ch][r]);
                }
            asm volatile("s_waitcnt lgkmcnt(0)" ::: "memory");
            int row = l >> 1;
            #pragma unroll
            for (int c = 0; c < 4; c++) {
                int col = (4 * (l & 1) + c) * 8;
                bf16x8 ov = *(const bf16x8*)((const char*)Ol + row * 144 + col * 2);
                *(bf16x8*)&ob[(size_t)(q0 + row) * 64 + col] = ov;
            }
        }
        __syncthreads();
    }
}

// ---------------------------------------------------------------------------
extern "C" void kernel_launch(void* const* d_in, const int* in_sizes, int n_in,
                              void* d_out, int out_size, void* d_ws, size_t ws_size,
                              hipStream_t stream) {
    const float* x      = (const float*)d_in[0];
    // d_in[1] = padding_mask (all true) - unused
    const float* W_attn = (const float*)d_in[2];
    const float* b_attn = (const float*)d_in[3];
    const float* W_proj = (const float*)d_in[4];
    const float* b_proj = (const float*)d_in[5];
    float* out = (float*)d_out;

    char* ws = (char*)d_ws;
    unsigned short* Xb  = (unsigned short*)(ws);               // 16.78 MB
    unsigned short* Wat = (unsigned short*)(ws + 16777216);    //  6.29 MB [3072][1024]
    unsigned short* Wpt = (unsigned short*)(ws + 23068672);    //  2.10 MB [1024][1024]
    unsigned short* Qb  = (unsigned short*)(ws + 25165824);    // 16.78 MB [B,H,S,HD]
    unsigned short* Kb  = (unsigned short*)(ws + 41943040);
    unsigned short* Vb  = (unsigned short*)(ws + 58720256);
    unsigned short* AOb = (unsigned short*)(ws + 75497472);    // 16.78 MB

    convert_x<<<8192, 256, 0, stream>>>(x, Xb);
    convert_wt<<<dim3(48, 16), 256, 0, stream>>>(W_attn, Wat, 3072);
    convert_wt<<<dim3(16, 16), 256, 0, stream>>>(W_proj, Wpt, 1024);

    gemm_mfma<0><<<dim3(24, 64), 256, 0, stream>>>(Xb, Wat, b_attn, Qb, Kb, Vb, nullptr);
    attn_mfma<<<512, 512, 0, stream>>>(Qb, Kb, Vb, AOb);
    gemm_mfma<1><<<dim3(8, 64), 256, 0, stream>>>(AOb, Wpt, b_proj, nullptr, nullptr, nullptr, out);
}